// Round 11
// baseline (492.069 us; speedup 1.0000x reference)
//
#include <hip/hip_runtime.h>

#define SCAN_B 1024

using f16x8 = __attribute__((ext_vector_type(8))) _Float16;
using f32x4 = __attribute__((ext_vector_type(4))) float;
typedef _Float16 half4v __attribute__((ext_vector_type(4)));
typedef _Float16 half8v __attribute__((ext_vector_type(8)));

// ---------------- precompute kernels ----------------

__global__ void zero2_kernel(int* __restrict__ a, int* __restrict__ b, int n) {
  int i = blockIdx.x * blockDim.x + threadIdx.x;
  if (i < n) { a[i] = 0; b[i] = 0; }
}

__global__ void count_kernel(const int* __restrict__ ei, int* __restrict__ cnt, int E) {
  int i = blockIdx.x * blockDim.x + threadIdx.x;
  if (i < E) atomicAdd(&cnt[ei[E + i]], 1);
}

// scan over (cnt[i] + 1) (row length incl. self edge); also emits dinv = rsqrt(deg)
__global__ void scan1_kernel(const int* __restrict__ cnt, int* __restrict__ rowstart,
                             int* __restrict__ bsum, float* __restrict__ dinv, int n) {
  __shared__ int sm[SCAN_B];
  const int t = threadIdx.x;
  const int i = blockIdx.x * SCAN_B + t;
  int c = (i < n) ? cnt[i] : 0;
  if (i < n) dinv[i] = rsqrtf((float)(c + 1));
  int v = (i < n) ? (c + 1) : 0;
  sm[t] = v;
  __syncthreads();
  for (int off = 1; off < SCAN_B; off <<= 1) {
    int x = (t >= off) ? sm[t - off] : 0;
    __syncthreads();
    if (t >= off) sm[t] += x;
    __syncthreads();
  }
  if (i < n) rowstart[i] = sm[t] - v;
  if (t == SCAN_B - 1) bsum[blockIdx.x] = sm[t];
}

__global__ void scan2_kernel(int* __restrict__ bsum, int nb) {
  __shared__ int sm[SCAN_B];
  const int t = threadIdx.x;
  int v = (t < nb) ? bsum[t] : 0;
  sm[t] = v;
  __syncthreads();
  for (int off = 1; off < SCAN_B; off <<= 1) {
    int x = (t >= off) ? sm[t - off] : 0;
    __syncthreads();
    if (t >= off) sm[t] += x;
    __syncthreads();
  }
  if (t < nb) bsum[t] = sm[t] - v;
}

__global__ void scan3_kernel(int* __restrict__ rowstart, const int* __restrict__ bsum, int n) {
  int i = blockIdx.x * blockDim.x + threadIdx.x;
  if (i < n) rowstart[i] += bsum[i / SCAN_B];
}

// fused: real edges (i < E) + self edges (i >= E, n = i - E, last slot of row n)
__global__ void fillself_kernel(const int* __restrict__ ei, int* __restrict__ fillc,
                                const int* __restrict__ rowstart, const int* __restrict__ cnt,
                                const float* __restrict__ dinv, float2* __restrict__ ew,
                                int E, int N) {
  int i = blockIdx.x * blockDim.x + threadIdx.x;
  if (i < E) {
    int s = ei[i];
    int d = ei[E + i];
    int p = atomicAdd(&fillc[d], 1);
    ew[rowstart[d] + p] = make_float2(__int_as_float(s), dinv[s] * dinv[d]);
  } else if (i < E + N) {
    int n = i - E;
    float dn = dinv[n];
    ew[rowstart[n] + cnt[n]] = make_float2(__int_as_float(n), dn * dn);
  }
}

// both weights in one launch: W [K][N] fp32 -> transposed [N][K] fp16 (RNE)
__global__ void wconv2_kernel(const float* __restrict__ W1, _Float16* __restrict__ W1t, int K1, int N1,
                              const float* __restrict__ W2, _Float16* __restrict__ W2t, int K2, int N2) {
  int i = blockIdx.x * blockDim.x + threadIdx.x;
  const int n1 = K1 * N1;
  if (i < n1) {
    int k = i / N1, n = i % N1;
    W1t[(size_t)n * K1 + k] = (_Float16)W1[i];
  } else if (i < n1 + K2 * N2) {
    int j = i - n1;
    int k = j / N2, n = j % N2;
    W2t[(size_t)n * K2 + k] = (_Float16)W2[j];
  }
}

// ---------------- fp16 MFMA GEMM — barrier-free, direct fragment loads ----------------
// C[M x N] = A[M x K] @ B[K x N], BN == N. 512 threads = 8 waves (2 x 4),
// per-wave output 64 x (BN/4). 16x16x32 fragments are 8 k-contiguous elems/lane:
//   A: two float4 from x[row][kt+fq*8] (row-major, 128B segments, 4x L1 reuse)
//   B: one 16B load from L2-resident Wt[col][kt+fq*8]
// K-loop has NO LDS and NO barriers — waves independent, loads pipeline freely.
// LDS used only by the coalesced C epilogue.

template <int BM, int BN, typename CT>
__global__ void __launch_bounds__(512, 2)
gemm_mfma_kernel(const float* __restrict__ A, const _Float16* __restrict__ Wt,
                 CT* __restrict__ C, int M, int K) {
  constexpr int MR  = BM / 2 / 16;        // 4
  constexpr int NR  = BN / 4 / 16;        // 2 (BN=128) or 1 (BN=64)
  constexpr int N   = BN;
  constexpr int LDC = NR * 16 + 4;        // epilogue patch row stride (floats)

  __shared__ __align__(16) float cpatch[8 * 16 * LDC];

  const int tid  = threadIdx.x;
  const int lane = tid & 63;
  const int w    = tid >> 6;          // 0..7
  const int wm   = w >> 2;            // 0..1 (64 rows each)
  const int wn   = w & 3;             // 0..3
  const int fr   = lane & 15;
  const int fq   = lane >> 4;
  const int m0   = blockIdx.x * BM;

  // per-lane row/col bases (clamped loads; stores predicated on real gm)
  size_t abase[MR];
#pragma unroll
  for (int mi = 0; mi < MR; ++mi) {
    const int gm = m0 + wm * 64 + mi * 16 + fr;
    abase[mi] = (size_t)(gm < M ? gm : 0) * K;
  }
  size_t bbase[NR];
#pragma unroll
  for (int ni = 0; ni < NR; ++ni)
    bbase[ni] = (size_t)(wn * (NR * 16) + ni * 16 + fr) * K;

  f32x4 acc[MR][NR] = {};

#pragma unroll 4
  for (int kt = 0; kt < K; kt += 32) {
    const int k0 = kt + fq * 8;
    f16x8 bfrag[NR];
#pragma unroll
    for (int ni = 0; ni < NR; ++ni)
      bfrag[ni] = *(const f16x8*)&Wt[bbase[ni] + k0];
#pragma unroll
    for (int mi = 0; mi < MR; ++mi) {
      const float4 u = *(const float4*)&A[abase[mi] + k0];
      const float4 v = *(const float4*)&A[abase[mi] + k0 + 4];
      f16x8 afrag = {(_Float16)u.x, (_Float16)u.y, (_Float16)u.z, (_Float16)u.w,
                     (_Float16)v.x, (_Float16)v.y, (_Float16)v.z, (_Float16)v.w};
#pragma unroll
      for (int ni = 0; ni < NR; ++ni)
        acc[mi][ni] = __builtin_amdgcn_mfma_f32_16x16x32_f16(afrag, bfrag[ni], acc[mi][ni], 0, 0, 0);
    }
  }

  // ---- epilogue: per-wave LDS patch -> coalesced stores ----
  {
    float* cst = cpatch + (size_t)w * (16 * LDC);
    constexpr int CPR   = NR * 4;        // float4 chunks per patch row
    constexpr int EPASS = (16 * CPR + 63) / 64;
#pragma unroll
    for (int mi = 0; mi < MR; ++mi) {
      __builtin_amdgcn_s_barrier();      // wave-local patch: just order LDS reuse across mi
#pragma unroll
      for (int ni = 0; ni < NR; ++ni)
#pragma unroll
        for (int r = 0; r < 4; ++r)
          cst[(fq * 4 + r) * LDC + ni * 16 + fr] = acc[mi][ni][r];
#pragma unroll
      for (int p = 0; p < EPASS; ++p) {
        const int idx = p * 64 + lane;
        if (idx < 16 * CPR) {
          const int row = idx / CPR;
          const int ch  = idx % CPR;
          const int gm  = m0 + wm * 64 + mi * 16 + row;
          float4 v = *(const float4*)&cst[row * LDC + ch * 4];
          if (gm < M) {
            if constexpr (sizeof(CT) == 2) {
              half4v hv = {(_Float16)v.x, (_Float16)v.y, (_Float16)v.z, (_Float16)v.w};
              *(half4v*)&C[(size_t)gm * N + wn * (NR * 16) + ch * 4] = hv;
            } else {
              *(float4*)&C[(size_t)gm * N + wn * (NR * 16) + ch * 4] = v;
            }
          }
        }
      }
    }
  }
}

// ---------------- CSR pull aggregation over fp16 rows ----------------
// Lane loads 8 halfs (16B). F=128: 16 lanes/edge, 4 slots/wave; F=64: 8 lanes/edge, 8 slots.
// Unroll x4 -> up to 16 edges in flight per wave. fp32 accumulate, fp32 output.

template <int F>
__global__ void agg_kernel(const _Float16* __restrict__ hin, const int* __restrict__ rowstart,
                           const int* __restrict__ cnt, const float2* __restrict__ ew,
                           const float* __restrict__ bias, float* __restrict__ outp, int N) {
  constexpr int LPE = F / 8;    // lanes per edge
  constexpr int EPW = 64 / LPE; // edge slots per wave
  const int wave = (int)((blockIdx.x * (size_t)blockDim.x + threadIdx.x) >> 6);
  if (wave >= N) return;
  const int lane = threadIdx.x & 63;
  const int sub  = lane / LPE;
  const int c    = lane % LPE;
  const int n    = wave;

  const int beg = rowstart[n];
  const int end = beg + cnt[n] + 1;   // incl. self edge

  float acc[8] = {};
  int j = beg + sub;
  for (; j + 3 * EPW < end; j += 4 * EPW) {
    const float2 e0 = ew[j];
    const float2 e1 = ew[j + EPW];
    const float2 e2 = ew[j + 2 * EPW];
    const float2 e3 = ew[j + 3 * EPW];
    const half8v v0 = *(const half8v*)&hin[(size_t)__float_as_int(e0.x) * F + c * 8];
    const half8v v1 = *(const half8v*)&hin[(size_t)__float_as_int(e1.x) * F + c * 8];
    const half8v v2 = *(const half8v*)&hin[(size_t)__float_as_int(e2.x) * F + c * 8];
    const half8v v3 = *(const half8v*)&hin[(size_t)__float_as_int(e3.x) * F + c * 8];
#pragma unroll
    for (int i = 0; i < 8; ++i) {
      acc[i] = fmaf((float)v0[i], e0.y, acc[i]);
      acc[i] = fmaf((float)v1[i], e1.y, acc[i]);
      acc[i] = fmaf((float)v2[i], e2.y, acc[i]);
      acc[i] = fmaf((float)v3[i], e3.y, acc[i]);
    }
  }
  for (; j < end; j += EPW) {
    const float2 e = ew[j];
    const half8v v = *(const half8v*)&hin[(size_t)__float_as_int(e.x) * F + c * 8];
#pragma unroll
    for (int i = 0; i < 8; ++i) acc[i] = fmaf((float)v[i], e.y, acc[i]);
  }

  // reduce across edge slots
#pragma unroll
  for (int d = LPE; d < 64; d <<= 1)
#pragma unroll
    for (int i = 0; i < 8; ++i) acc[i] += __shfl_xor(acc[i], d);

  if (lane < LPE) {
    const float4 b0 = *(const float4*)&bias[c * 8];
    const float4 b1 = *(const float4*)&bias[c * 8 + 4];
    float4 r0, r1;
    r0.x = fmaxf(acc[0] + b0.x, 0.f);
    r0.y = fmaxf(acc[1] + b0.y, 0.f);
    r0.z = fmaxf(acc[2] + b0.z, 0.f);
    r0.w = fmaxf(acc[3] + b0.w, 0.f);
    r1.x = fmaxf(acc[4] + b1.x, 0.f);
    r1.y = fmaxf(acc[5] + b1.y, 0.f);
    r1.z = fmaxf(acc[6] + b1.z, 0.f);
    r1.w = fmaxf(acc[7] + b1.w, 0.f);
    *(float4*)&outp[(size_t)n * F + c * 8] = r0;
    *(float4*)&outp[(size_t)n * F + c * 8 + 4] = r1;
  }
}

// ---------------- launch ----------------

extern "C" void kernel_launch(void* const* d_in, const int* in_sizes, int n_in,
                              void* d_out, int out_size, void* d_ws, size_t ws_size,
                              hipStream_t stream) {
  const float* x  = (const float*)d_in[0];
  const int*   ei = (const int*)d_in[1];
  const float* W1 = (const float*)d_in[2];
  const float* b1 = (const float*)d_in[3];
  const float* W2 = (const float*)d_in[4];
  const float* b2 = (const float*)d_in[5];
  float* out = (float*)d_out;

  const int F1 = in_sizes[3];           // 128
  const int F2 = in_sizes[5];           // 64
  const int F0 = in_sizes[2] / F1;      // 512
  const int N  = in_sizes[0] / F0;      // 100000
  const int E  = in_sizes[1] / 2;       // 1600000

  char* ws = (char*)d_ws;
  size_t off = 0;
  auto alloc = [&](size_t bytes) -> void* {
    void* p = ws + off;
    off = (off + bytes + 255) & ~(size_t)255;
    return p;
  };

  int*    cnt      = (int*)alloc((size_t)N * 4);
  int*    fillc    = (int*)alloc((size_t)N * 4);
  int*    rowstart = (int*)alloc((size_t)N * 4);
  float*  dinv     = (float*)alloc((size_t)N * 4);
  const int nb     = (N + SCAN_B - 1) / SCAN_B;
  int*    bsum     = (int*)alloc((size_t)nb * 4);
  float2* ew       = (float2*)alloc(((size_t)E + N) * 8);
  _Float16* h      = (_Float16*)alloc((size_t)N * F1 * 2);  // fp16 GEMM1 out
  float*  h1       = (float*)alloc((size_t)N * F1 * 4);     // fp32 agg1 out
  _Float16* h2     = h;  // fp16 GEMM2 out, reuses h (dead after agg1)
  _Float16* W1t    = (_Float16*)alloc((size_t)F0 * F1 * 2);
  _Float16* W2t    = (_Float16*)alloc((size_t)F1 * F2 * 2);

  zero2_kernel<<<(N + 255) / 256, 256, 0, stream>>>(cnt, fillc, N);
  count_kernel<<<(E + 255) / 256, 256, 0, stream>>>(ei, cnt, E);
  scan1_kernel<<<nb, SCAN_B, 0, stream>>>(cnt, rowstart, bsum, dinv, N);
  scan2_kernel<<<1, SCAN_B, 0, stream>>>(bsum, nb);
  scan3_kernel<<<(N + 255) / 256, 256, 0, stream>>>(rowstart, bsum, N);
  fillself_kernel<<<(E + N + 255) / 256, 256, 0, stream>>>(ei, fillc, rowstart, cnt, dinv, ew, E, N);
  wconv2_kernel<<<(F0 * F1 + F1 * F2 + 255) / 256, 256, 0, stream>>>(
      W1, W1t, F0, F1, W2, W2t, F1, F2);

  // layer 1: h = fp16(x@W1) ; h1 = relu(agg(h) + b1)  (fp32)
  gemm_mfma_kernel<128, 128, _Float16><<<(N + 127) / 128, 512, 0, stream>>>(x, W1t, h, N, F0);
  {
    const long blocks = ((long)N * 64 + 255) / 256;
    agg_kernel<128><<<(int)blocks, 256, 0, stream>>>(h, rowstart, cnt, ew, b1, h1, N);
  }

  // layer 2: h2 = fp16(h1@W2) ; out = relu(agg(h2) + b2)
  gemm_mfma_kernel<128, 64, _Float16><<<(N + 127) / 128, 512, 0, stream>>>(h1, W2t, h2, N, F1);
  {
    const long blocks = ((long)N * 64 + 255) / 256;
    agg_kernel<64><<<(int)blocks, 256, 0, stream>>>(h2, rowstart, cnt, ew, b2, out, N);
  }
}

// Round 12
// 374.422 us; speedup vs baseline: 1.3142x; 1.3142x over previous
//
#include <hip/hip_runtime.h>

#define SCAN_B 1024

using f16x8 = __attribute__((ext_vector_type(8))) _Float16;
using f32x4 = __attribute__((ext_vector_type(4))) float;
typedef _Float16 half4v __attribute__((ext_vector_type(4)));
typedef _Float16 half8v __attribute__((ext_vector_type(8)));

// ---------------- precompute kernels ----------------

__global__ void zero2_kernel(int* __restrict__ a, int* __restrict__ b, int n) {
  int i = blockIdx.x * blockDim.x + threadIdx.x;
  if (i < n) { a[i] = 0; b[i] = 0; }
}

__global__ void count_kernel(const int* __restrict__ ei, int* __restrict__ cnt, int E) {
  int i = blockIdx.x * blockDim.x + threadIdx.x;
  if (i < E) atomicAdd(&cnt[ei[E + i]], 1);
}

// scan over (cnt[i] + 1) (row length incl. self edge); also emits dinv = rsqrt(deg)
__global__ void scan1_kernel(const int* __restrict__ cnt, int* __restrict__ rowstart,
                             int* __restrict__ bsum, float* __restrict__ dinv, int n) {
  __shared__ int sm[SCAN_B];
  const int t = threadIdx.x;
  const int i = blockIdx.x * SCAN_B + t;
  int c = (i < n) ? cnt[i] : 0;
  if (i < n) dinv[i] = rsqrtf((float)(c + 1));
  int v = (i < n) ? (c + 1) : 0;
  sm[t] = v;
  __syncthreads();
  for (int off = 1; off < SCAN_B; off <<= 1) {
    int x = (t >= off) ? sm[t - off] : 0;
    __syncthreads();
    if (t >= off) sm[t] += x;
    __syncthreads();
  }
  if (i < n) rowstart[i] = sm[t] - v;
  if (t == SCAN_B - 1) bsum[blockIdx.x] = sm[t];
}

__global__ void scan2_kernel(int* __restrict__ bsum, int nb) {
  __shared__ int sm[SCAN_B];
  const int t = threadIdx.x;
  int v = (t < nb) ? bsum[t] : 0;
  sm[t] = v;
  __syncthreads();
  for (int off = 1; off < SCAN_B; off <<= 1) {
    int x = (t >= off) ? sm[t - off] : 0;
    __syncthreads();
    if (t >= off) sm[t] += x;
    __syncthreads();
  }
  if (t < nb) bsum[t] = sm[t] - v;
}

__global__ void scan3_kernel(int* __restrict__ rowstart, const int* __restrict__ bsum, int n) {
  int i = blockIdx.x * blockDim.x + threadIdx.x;
  if (i < n) rowstart[i] += bsum[i / SCAN_B];
}

// fused: real edges (i < E) + self edges (i >= E, n = i - E, last slot of row n)
__global__ void fillself_kernel(const int* __restrict__ ei, int* __restrict__ fillc,
                                const int* __restrict__ rowstart, const int* __restrict__ cnt,
                                const float* __restrict__ dinv, float2* __restrict__ ew,
                                int E, int N) {
  int i = blockIdx.x * blockDim.x + threadIdx.x;
  if (i < E) {
    int s = ei[i];
    int d = ei[E + i];
    int p = atomicAdd(&fillc[d], 1);
    ew[rowstart[d] + p] = make_float2(__int_as_float(s), dinv[s] * dinv[d]);
  } else if (i < E + N) {
    int n = i - E;
    float dn = dinv[n];
    ew[rowstart[n] + cnt[n]] = make_float2(__int_as_float(n), dn * dn);
  }
}

// both weights in one launch: W [K][N] fp32 -> transposed [N][K] fp16 (RNE)
__global__ void wconv2_kernel(const float* __restrict__ W1, _Float16* __restrict__ W1t, int K1, int N1,
                              const float* __restrict__ W2, _Float16* __restrict__ W2t, int K2, int N2) {
  int i = blockIdx.x * blockDim.x + threadIdx.x;
  const int n1 = K1 * N1;
  if (i < n1) {
    int k = i / N1, n = i % N1;
    W1t[(size_t)n * K1 + k] = (_Float16)W1[i];
  } else if (i < n1 + K2 * N2) {
    int j = i - n1;
    int k = j / N2, n = j % N2;
    W2t[(size_t)n * K2 + k] = (_Float16)W2[j];
  }
}

// ---------------- fp16 MFMA GEMM, 8-wave, BK=64, reg-prefetch ----------------
// C[M x N] = A[M x K] @ B[K x N], BN == N. 512 threads = 8 waves (2 x 4).
// A fp32 -> fp16 cvt in-kernel -> LDS (coalesced tile loads); B pre-transposed
// Wt [N][K] fp16 -> LDS. BK=64 halves barrier count vs BK=32 and doubles
// per-tile MLP. Next tile's loads issued after staging, drain under MFMAs.

template <int BM, int BN, typename CT>
__global__ void __launch_bounds__(512, 2)
gemm_mfma_kernel(const float* __restrict__ A, const _Float16* __restrict__ Wt,
                 CT* __restrict__ C, int M, int K) {
  constexpr int BK    = 64;
  constexpr int LDK   = 72;                // fp16 elems per LDS row (144B)
  constexpr int MR    = BM / 2 / 16;       // 4
  constexpr int NR    = BN / 4 / 16;       // 2 (BN=128) or 1 (BN=64)
  constexpr int N     = BN;
  constexpr int LDC   = NR * 16 + 4;       // epilogue patch row stride (floats)
  constexpr int SMA   = (BM + BN) * LDK * 2;
  constexpr int SME   = 8 * 16 * LDC * 4;
  constexpr int SMEM  = SMA > SME ? SMA : SME;
  constexpr int BITER = (BN * 8) / 512;    // B 16B-chunks per thread (2 or 1)

  __shared__ __align__(16) char smem[SMEM];
  _Float16* Asm = (_Float16*)smem;
  _Float16* Bsm = Asm + (size_t)BM * LDK;

  const int tid  = threadIdx.x;
  const int lane = tid & 63;
  const int w    = tid >> 6;          // 0..7
  const int wm   = w >> 2;            // 0..1 (64 rows each)
  const int wn   = w & 3;             // 0..3
  const int fr   = lane & 15;
  const int fq   = lane >> 4;
  const int m0   = blockIdx.x * BM;

  const int a_c = tid & 15;           // k-chunk (4 floats), 16 chunks = 64 k
  const int a_m = tid >> 4;           // row 0..31 (4 passes)

  float4 av[4];
  uint4  btv[BITER];

  auto loadA = [&](int kt) {
#pragma unroll
    for (int p = 0; p < 4; ++p) {
      const int gm = m0 + a_m + 32 * p;
      av[p] = (gm < M) ? *(const float4*)&A[(size_t)gm * K + kt + 4 * a_c]
                       : make_float4(0.f, 0.f, 0.f, 0.f);
    }
  };
  auto loadB = [&](int kt) {
#pragma unroll
    for (int i = 0; i < BITER; ++i) {
      const int idx = tid + i * 512;
      const int r = idx >> 3, j = idx & 7;    // 8 x 16B chunks per 64-k row
      btv[i] = *(const uint4*)&Wt[(size_t)r * K + kt + 8 * j];
    }
  };

  f32x4 acc[MR][NR] = {};

  loadA(0);
  loadB(0);

  for (int kt = 0; kt < K; kt += BK) {
    __syncthreads();   // previous tile's LDS frag reads complete

    // ---- A cvt + store; B copy ----
#pragma unroll
    for (int p = 0; p < 4; ++p) {
      const int r = a_m + 32 * p;
      half4v hv = {(_Float16)av[p].x, (_Float16)av[p].y, (_Float16)av[p].z, (_Float16)av[p].w};
      *(half4v*)((char*)Asm + r * (LDK * 2) + a_c * 8) = hv;
    }
#pragma unroll
    for (int i = 0; i < BITER; ++i) {
      const int idx = tid + i * 512;
      const int r = idx >> 3, j = idx & 7;
      *(uint4*)((char*)Bsm + r * (LDK * 2) + 16 * j) = btv[i];
    }
    __syncthreads();

    // ---- issue next tile's loads; they drain under the MFMA section ----
    if (kt + BK < K) {
      loadA(kt + BK);
      loadB(kt + BK);
    }

    // ---- fragments + MFMA (2 k-subtiles of 32) ----
    f16x8 bfrag[NR][2];
#pragma unroll
    for (int ni = 0; ni < NR; ++ni) {
      const int r = wn * (NR * 16) + ni * 16 + fr;
#pragma unroll
      for (int ks = 0; ks < 2; ++ks)
        bfrag[ni][ks] = *(const f16x8*)((const char*)Bsm + r * (LDK * 2) + ks * 64 + fq * 16);
    }
#pragma unroll
    for (int mi = 0; mi < MR; ++mi) {
      const int r = wm * 64 + mi * 16 + fr;
      f16x8 af0 = *(const f16x8*)((const char*)Asm + r * (LDK * 2) + fq * 16);
      f16x8 af1 = *(const f16x8*)((const char*)Asm + r * (LDK * 2) + 64 + fq * 16);
#pragma unroll
      for (int ni = 0; ni < NR; ++ni) {
        acc[mi][ni] = __builtin_amdgcn_mfma_f32_16x16x32_f16(af0, bfrag[ni][0], acc[mi][ni], 0, 0, 0);
        acc[mi][ni] = __builtin_amdgcn_mfma_f32_16x16x32_f16(af1, bfrag[ni][1], acc[mi][ni], 0, 0, 0);
      }
    }
  }

  // ---- epilogue: per-wave LDS patch -> coalesced stores (patch is wave-local) ----
  __syncthreads();   // all frag reads done; smem reused
  {
    float* cst = (float*)smem + (size_t)w * (16 * LDC);
    constexpr int CPR   = NR * 4;        // float4 chunks per patch row
    constexpr int EPASS = (16 * CPR + 63) / 64;
#pragma unroll
    for (int mi = 0; mi < MR; ++mi) {
#pragma unroll
      for (int ni = 0; ni < NR; ++ni)
#pragma unroll
        for (int r = 0; r < 4; ++r)
          cst[(fq * 4 + r) * LDC + ni * 16 + fr] = acc[mi][ni][r];
#pragma unroll
      for (int p = 0; p < EPASS; ++p) {
        const int idx = p * 64 + lane;
        if (idx < 16 * CPR) {
          const int row = idx / CPR;
          const int ch  = idx % CPR;
          const int gm  = m0 + wm * 64 + mi * 16 + row;
          float4 v = *(const float4*)&cst[row * LDC + ch * 4];
          if (gm < M) {
            if constexpr (sizeof(CT) == 2) {
              half4v hv = {(_Float16)v.x, (_Float16)v.y, (_Float16)v.z, (_Float16)v.w};
              *(half4v*)&C[(size_t)gm * N + wn * (NR * 16) + ch * 4] = hv;
            } else {
              *(float4*)&C[(size_t)gm * N + wn * (NR * 16) + ch * 4] = v;
            }
          }
        }
      }
    }
  }
}

// ---------------- CSR pull aggregation over fp16 rows ----------------
// Lane loads 8 halfs (16B). F=128: 16 lanes/edge, 4 slots/wave; F=64: 8 lanes/edge, 8 slots.
// Unroll x4 -> up to 16 edges in flight per wave. fp32 accumulate, fp32 output.

template <int F>
__global__ void agg_kernel(const _Float16* __restrict__ hin, const int* __restrict__ rowstart,
                           const int* __restrict__ cnt, const float2* __restrict__ ew,
                           const float* __restrict__ bias, float* __restrict__ outp, int N) {
  constexpr int LPE = F / 8;    // lanes per edge
  constexpr int EPW = 64 / LPE; // edge slots per wave
  const int wave = (int)((blockIdx.x * (size_t)blockDim.x + threadIdx.x) >> 6);
  if (wave >= N) return;
  const int lane = threadIdx.x & 63;
  const int sub  = lane / LPE;
  const int c    = lane % LPE;
  const int n    = wave;

  const int beg = rowstart[n];
  const int end = beg + cnt[n] + 1;   // incl. self edge

  float acc[8] = {};
  int j = beg + sub;
  for (; j + 3 * EPW < end; j += 4 * EPW) {
    const float2 e0 = ew[j];
    const float2 e1 = ew[j + EPW];
    const float2 e2 = ew[j + 2 * EPW];
    const float2 e3 = ew[j + 3 * EPW];
    const half8v v0 = *(const half8v*)&hin[(size_t)__float_as_int(e0.x) * F + c * 8];
    const half8v v1 = *(const half8v*)&hin[(size_t)__float_as_int(e1.x) * F + c * 8];
    const half8v v2 = *(const half8v*)&hin[(size_t)__float_as_int(e2.x) * F + c * 8];
    const half8v v3 = *(const half8v*)&hin[(size_t)__float_as_int(e3.x) * F + c * 8];
#pragma unroll
    for (int i = 0; i < 8; ++i) {
      acc[i] = fmaf((float)v0[i], e0.y, acc[i]);
      acc[i] = fmaf((float)v1[i], e1.y, acc[i]);
      acc[i] = fmaf((float)v2[i], e2.y, acc[i]);
      acc[i] = fmaf((float)v3[i], e3.y, acc[i]);
    }
  }
  for (; j < end; j += EPW) {
    const float2 e = ew[j];
    const half8v v = *(const half8v*)&hin[(size_t)__float_as_int(e.x) * F + c * 8];
#pragma unroll
    for (int i = 0; i < 8; ++i) acc[i] = fmaf((float)v[i], e.y, acc[i]);
  }

  // reduce across edge slots
#pragma unroll
  for (int d = LPE; d < 64; d <<= 1)
#pragma unroll
    for (int i = 0; i < 8; ++i) acc[i] += __shfl_xor(acc[i], d);

  if (lane < LPE) {
    const float4 b0 = *(const float4*)&bias[c * 8];
    const float4 b1 = *(const float4*)&bias[c * 8 + 4];
    float4 r0, r1;
    r0.x = fmaxf(acc[0] + b0.x, 0.f);
    r0.y = fmaxf(acc[1] + b0.y, 0.f);
    r0.z = fmaxf(acc[2] + b0.z, 0.f);
    r0.w = fmaxf(acc[3] + b0.w, 0.f);
    r1.x = fmaxf(acc[4] + b1.x, 0.f);
    r1.y = fmaxf(acc[5] + b1.y, 0.f);
    r1.z = fmaxf(acc[6] + b1.z, 0.f);
    r1.w = fmaxf(acc[7] + b1.w, 0.f);
    *(float4*)&outp[(size_t)n * F + c * 8] = r0;
    *(float4*)&outp[(size_t)n * F + c * 8 + 4] = r1;
  }
}

// ---------------- launch ----------------

extern "C" void kernel_launch(void* const* d_in, const int* in_sizes, int n_in,
                              void* d_out, int out_size, void* d_ws, size_t ws_size,
                              hipStream_t stream) {
  const float* x  = (const float*)d_in[0];
  const int*   ei = (const int*)d_in[1];
  const float* W1 = (const float*)d_in[2];
  const float* b1 = (const float*)d_in[3];
  const float* W2 = (const float*)d_in[4];
  const float* b2 = (const float*)d_in[5];
  float* out = (float*)d_out;

  const int F1 = in_sizes[3];           // 128
  const int F2 = in_sizes[5];           // 64
  const int F0 = in_sizes[2] / F1;      // 512
  const int N  = in_sizes[0] / F0;      // 100000
  const int E  = in_sizes[1] / 2;       // 1600000

  char* ws = (char*)d_ws;
  size_t off = 0;
  auto alloc = [&](size_t bytes) -> void* {
    void* p = ws + off;
    off = (off + bytes + 255) & ~(size_t)255;
    return p;
  };

  int*    cnt      = (int*)alloc((size_t)N * 4);
  int*    fillc    = (int*)alloc((size_t)N * 4);
  int*    rowstart = (int*)alloc((size_t)N * 4);
  float*  dinv     = (float*)alloc((size_t)N * 4);
  const int nb     = (N + SCAN_B - 1) / SCAN_B;
  int*    bsum     = (int*)alloc((size_t)nb * 4);
  float2* ew       = (float2*)alloc(((size_t)E + N) * 8);
  _Float16* h      = (_Float16*)alloc((size_t)N * F1 * 2);  // fp16 GEMM1 out
  float*  h1       = (float*)alloc((size_t)N * F1 * 4);     // fp32 agg1 out
  _Float16* h2     = h;  // fp16 GEMM2 out, reuses h (dead after agg1)
  _Float16* W1t    = (_Float16*)alloc((size_t)F0 * F1 * 2);
  _Float16* W2t    = (_Float16*)alloc((size_t)F1 * F2 * 2);

  zero2_kernel<<<(N + 255) / 256, 256, 0, stream>>>(cnt, fillc, N);
  count_kernel<<<(E + 255) / 256, 256, 0, stream>>>(ei, cnt, E);
  scan1_kernel<<<nb, SCAN_B, 0, stream>>>(cnt, rowstart, bsum, dinv, N);
  scan2_kernel<<<1, SCAN_B, 0, stream>>>(bsum, nb);
  scan3_kernel<<<(N + 255) / 256, 256, 0, stream>>>(rowstart, bsum, N);
  fillself_kernel<<<(E + N + 255) / 256, 256, 0, stream>>>(ei, fillc, rowstart, cnt, dinv, ew, E, N);
  wconv2_kernel<<<(F0 * F1 + F1 * F2 + 255) / 256, 256, 0, stream>>>(
      W1, W1t, F0, F1, W2, W2t, F1, F2);

  // layer 1: h = fp16(x@W1) ; h1 = relu(agg(h) + b1)  (fp32)
  gemm_mfma_kernel<128, 128, _Float16><<<(N + 127) / 128, 512, 0, stream>>>(x, W1t, h, N, F0);
  {
    const long blocks = ((long)N * 64 + 255) / 256;
    agg_kernel<128><<<(int)blocks, 256, 0, stream>>>(h, rowstart, cnt, ew, b1, h1, N);
  }

  // layer 2: h2 = fp16(h1@W2) ; out = relu(agg(h2) + b2)
  gemm_mfma_kernel<128, 64, _Float16><<<(N + 127) / 128, 512, 0, stream>>>(h1, W2t, h2, N, F1);
  {
    const long blocks = ((long)N * 64 + 255) / 256;
    agg_kernel<64><<<(int)blocks, 256, 0, stream>>>(h2, rowstart, cnt, ew, b2, out, N);
  }
}

// Round 13
// 349.525 us; speedup vs baseline: 1.4078x; 1.0712x over previous
//
#include <hip/hip_runtime.h>

#define SCAN_B 1024

using f16x8 = __attribute__((ext_vector_type(8))) _Float16;
using f32x4 = __attribute__((ext_vector_type(4))) float;
typedef _Float16 half4v __attribute__((ext_vector_type(4)));
typedef _Float16 half8v __attribute__((ext_vector_type(8)));

// ---------------- precompute kernels ----------------

__global__ void zero2_kernel(int* __restrict__ a, int* __restrict__ b, int n) {
  int i = blockIdx.x * blockDim.x + threadIdx.x;
  if (i < n) { a[i] = 0; b[i] = 0; }
}

__global__ void count_kernel(const int* __restrict__ ei, int* __restrict__ cnt, int E) {
  int i = blockIdx.x * blockDim.x + threadIdx.x;
  if (i < E) atomicAdd(&cnt[ei[E + i]], 1);
}

// scan over (cnt[i] + 1) (row length incl. self edge); also emits dinv = rsqrt(deg)
__global__ void scan1_kernel(const int* __restrict__ cnt, int* __restrict__ rowstart,
                             int* __restrict__ bsum, float* __restrict__ dinv, int n) {
  __shared__ int sm[SCAN_B];
  const int t = threadIdx.x;
  const int i = blockIdx.x * SCAN_B + t;
  int c = (i < n) ? cnt[i] : 0;
  if (i < n) dinv[i] = rsqrtf((float)(c + 1));
  int v = (i < n) ? (c + 1) : 0;
  sm[t] = v;
  __syncthreads();
  for (int off = 1; off < SCAN_B; off <<= 1) {
    int x = (t >= off) ? sm[t - off] : 0;
    __syncthreads();
    if (t >= off) sm[t] += x;
    __syncthreads();
  }
  if (i < n) rowstart[i] = sm[t] - v;
  if (t == SCAN_B - 1) bsum[blockIdx.x] = sm[t];
}

__global__ void scan2_kernel(int* __restrict__ bsum, int nb) {
  __shared__ int sm[SCAN_B];
  const int t = threadIdx.x;
  int v = (t < nb) ? bsum[t] : 0;
  sm[t] = v;
  __syncthreads();
  for (int off = 1; off < SCAN_B; off <<= 1) {
    int x = (t >= off) ? sm[t - off] : 0;
    __syncthreads();
    if (t >= off) sm[t] += x;
    __syncthreads();
  }
  if (t < nb) bsum[t] = sm[t] - v;
}

__global__ void scan3_kernel(int* __restrict__ rowstart, const int* __restrict__ bsum, int n) {
  int i = blockIdx.x * blockDim.x + threadIdx.x;
  if (i < n) rowstart[i] += bsum[i / SCAN_B];
}

// fused: real edges (i < E) + self edges (i >= E, n = i - E, last slot of row n)
__global__ void fillself_kernel(const int* __restrict__ ei, int* __restrict__ fillc,
                                const int* __restrict__ rowstart, const int* __restrict__ cnt,
                                const float* __restrict__ dinv, float2* __restrict__ ew,
                                int E, int N) {
  int i = blockIdx.x * blockDim.x + threadIdx.x;
  if (i < E) {
    int s = ei[i];
    int d = ei[E + i];
    int p = atomicAdd(&fillc[d], 1);
    ew[rowstart[d] + p] = make_float2(__int_as_float(s), dinv[s] * dinv[d]);
  } else if (i < E + N) {
    int n = i - E;
    float dn = dinv[n];
    ew[rowstart[n] + cnt[n]] = make_float2(__int_as_float(n), dn * dn);
  }
}

// both weights in one launch: W [K][N] fp32 -> transposed [N][K] fp16 (RNE)
__global__ void wconv2_kernel(const float* __restrict__ W1, _Float16* __restrict__ W1t, int K1, int N1,
                              const float* __restrict__ W2, _Float16* __restrict__ W2t, int K2, int N2) {
  int i = blockIdx.x * blockDim.x + threadIdx.x;
  const int n1 = K1 * N1;
  if (i < n1) {
    int k = i / N1, n = i % N1;
    W1t[(size_t)n * K1 + k] = (_Float16)W1[i];
  } else if (i < n1 + K2 * N2) {
    int j = i - n1;
    int k = j / N2, n = j % N2;
    W2t[(size_t)n * K2 + k] = (_Float16)W2[j];
  }
}

// ---------------- fp16 MFMA GEMM, 8-wave, BK=32, reg-prefetch ----------------
// C[M x N] = A[M x K] @ B[K x N], BN == N. 512 threads = 8 waves (2 x 4).
// AT = float (cvt->fp16 during staging) or _Float16 (straight 16B copies).
// B pre-transposed Wt [N][K] fp16 -> LDS. Next tile's loads issued after
// staging, drain under the MFMAs. Epilogue: per-wave LDS patch -> coalesced.

template <int BM, int BN, typename AT, typename CT>
__global__ void __launch_bounds__(512, 2)
gemm_mfma_kernel(const AT* __restrict__ A, const _Float16* __restrict__ Wt,
                 CT* __restrict__ C, int M, int K) {
  constexpr int BK   = 32;
  constexpr int LDK  = 40;                 // fp16 elems per LDS row (80B)
  constexpr int MR   = BM / 2 / 16;        // 4
  constexpr int NR   = BN / 4 / 16;        // 2 (BN=128) or 1 (BN=64)
  constexpr int N    = BN;
  constexpr int LDC  = NR * 16 + 4;        // epilogue patch row stride (floats)
  constexpr int SMA  = (BM + BN) * LDK * 2;
  constexpr int SME  = 8 * 16 * LDC * 4;
  constexpr int SMEM = SMA > SME ? SMA : SME;

  __shared__ __align__(16) char smem[SMEM];
  _Float16* Asm = (_Float16*)smem;
  _Float16* Bsm = Asm + (size_t)BM * LDK;

  const int tid  = threadIdx.x;
  const int lane = tid & 63;
  const int w    = tid >> 6;          // 0..7
  const int wm   = w >> 2;            // 0..1 (64 rows each)
  const int wn   = w & 3;             // 0..3
  const int fr   = lane & 15;
  const int fq   = lane >> 4;
  const int m0   = blockIdx.x * BM;

  constexpr bool A32 = sizeof(AT) == 4;
  // A loader map: fp32 -> 8 chunks of 4 floats (2 row passes); fp16 -> 4 chunks of 8 halfs (1 pass)
  const int a_c = A32 ? (tid & 7) : (tid & 3);
  const int a_m = A32 ? (tid >> 3) : (tid >> 2);
  const int br  = tid >> 2;           // B row 0..127
  const int bj  = tid & 3;            // B 16B chunk (8 fp16)

  float4 av32[2];
  uint4  av16;
  uint4  bt;

  auto loadA = [&](int kt) {
    if constexpr (A32) {
#pragma unroll
      for (int p = 0; p < 2; ++p) {
        const int gm = m0 + a_m + 64 * p;
        av32[p] = (gm < M) ? *(const float4*)&A[(size_t)gm * K + kt + 4 * a_c]
                           : make_float4(0.f, 0.f, 0.f, 0.f);
      }
    } else {
      const int gm = m0 + a_m;
      av16 = (gm < M) ? *(const uint4*)&A[(size_t)gm * K + kt + 8 * a_c]
                      : make_uint4(0u, 0u, 0u, 0u);
    }
  };
  auto loadB = [&](int kt) {
    if (tid < BN * 4) bt = *(const uint4*)&Wt[(size_t)br * K + kt + 8 * bj];
  };

  f32x4 acc[MR][NR] = {};

  loadA(0);
  loadB(0);

  for (int kt = 0; kt < K; kt += BK) {
    __syncthreads();   // previous tile's LDS frag reads complete

    // ---- A staging; B copy ----
    if constexpr (A32) {
#pragma unroll
      for (int p = 0; p < 2; ++p) {
        const int r = a_m + 64 * p;
        half4v hv = {(_Float16)av32[p].x, (_Float16)av32[p].y,
                     (_Float16)av32[p].z, (_Float16)av32[p].w};
        *(half4v*)((char*)Asm + r * (LDK * 2) + a_c * 8) = hv;
      }
    } else {
      *(uint4*)((char*)Asm + a_m * (LDK * 2) + a_c * 16) = av16;
    }
    if (tid < BN * 4) *(uint4*)((char*)Bsm + br * (LDK * 2) + 16 * bj) = bt;
    __syncthreads();

    // ---- issue next tile's loads; they drain under the MFMA section ----
    if (kt + BK < K) {
      loadA(kt + BK);
      loadB(kt + BK);
    }

    // ---- fragments + MFMA ----
    f16x8 bfrag[NR];
#pragma unroll
    for (int ni = 0; ni < NR; ++ni) {
      const int r = wn * (NR * 16) + ni * 16 + fr;
      bfrag[ni] = *(const f16x8*)((const char*)Bsm + r * (LDK * 2) + fq * 16);
    }
#pragma unroll
    for (int mi = 0; mi < MR; ++mi) {
      const int r = wm * 64 + mi * 16 + fr;
      f16x8 afrag = *(const f16x8*)((const char*)Asm + r * (LDK * 2) + fq * 16);
#pragma unroll
      for (int ni = 0; ni < NR; ++ni)
        acc[mi][ni] = __builtin_amdgcn_mfma_f32_16x16x32_f16(afrag, bfrag[ni], acc[mi][ni], 0, 0, 0);
    }
  }

  // ---- epilogue: per-wave LDS patch -> coalesced stores ----
  __syncthreads();   // all frag reads done; smem reused
  {
    float* cst = (float*)smem + (size_t)w * (16 * LDC);
    constexpr int CPR   = NR * 4;        // float4 chunks per patch row
    constexpr int EPASS = (16 * CPR + 63) / 64;
#pragma unroll
    for (int mi = 0; mi < MR; ++mi) {
#pragma unroll
      for (int ni = 0; ni < NR; ++ni)
#pragma unroll
        for (int r = 0; r < 4; ++r)
          cst[(fq * 4 + r) * LDC + ni * 16 + fr] = acc[mi][ni][r];
#pragma unroll
      for (int p = 0; p < EPASS; ++p) {
        const int idx = p * 64 + lane;
        if (idx < 16 * CPR) {
          const int row = idx / CPR;
          const int ch  = idx % CPR;
          const int gm  = m0 + wm * 64 + mi * 16 + row;
          float4 v = *(const float4*)&cst[row * LDC + ch * 4];
          if (gm < M) {
            if constexpr (sizeof(CT) == 2) {
              half4v hv = {(_Float16)v.x, (_Float16)v.y, (_Float16)v.z, (_Float16)v.w};
              *(half4v*)&C[(size_t)gm * N + wn * (NR * 16) + ch * 4] = hv;
            } else {
              *(float4*)&C[(size_t)gm * N + wn * (NR * 16) + ch * 4] = v;
            }
          }
        }
      }
    }
  }
}

// ---------------- CSR pull aggregation over fp16 rows ----------------
// Lane loads 8 halfs (16B). F=128: 16 lanes/edge, 4 slots/wave; F=64: 8 lanes/edge, 8 slots.
// Unroll x4. fp32 accumulate; output type OT = float or _Float16 (RNE).

template <int F, typename OT>
__global__ void agg_kernel(const _Float16* __restrict__ hin, const int* __restrict__ rowstart,
                           const int* __restrict__ cnt, const float2* __restrict__ ew,
                           const float* __restrict__ bias, OT* __restrict__ outp, int N) {
  constexpr int LPE = F / 8;    // lanes per edge
  constexpr int EPW = 64 / LPE; // edge slots per wave
  const int wave = (int)((blockIdx.x * (size_t)blockDim.x + threadIdx.x) >> 6);
  if (wave >= N) return;
  const int lane = threadIdx.x & 63;
  const int sub  = lane / LPE;
  const int c    = lane % LPE;
  const int n    = wave;

  const int beg = rowstart[n];
  const int end = beg + cnt[n] + 1;   // incl. self edge

  float acc[8] = {};
  int j = beg + sub;
  for (; j + 3 * EPW < end; j += 4 * EPW) {
    const float2 e0 = ew[j];
    const float2 e1 = ew[j + EPW];
    const float2 e2 = ew[j + 2 * EPW];
    const float2 e3 = ew[j + 3 * EPW];
    const half8v v0 = *(const half8v*)&hin[(size_t)__float_as_int(e0.x) * F + c * 8];
    const half8v v1 = *(const half8v*)&hin[(size_t)__float_as_int(e1.x) * F + c * 8];
    const half8v v2 = *(const half8v*)&hin[(size_t)__float_as_int(e2.x) * F + c * 8];
    const half8v v3 = *(const half8v*)&hin[(size_t)__float_as_int(e3.x) * F + c * 8];
#pragma unroll
    for (int i = 0; i < 8; ++i) {
      acc[i] = fmaf((float)v0[i], e0.y, acc[i]);
      acc[i] = fmaf((float)v1[i], e1.y, acc[i]);
      acc[i] = fmaf((float)v2[i], e2.y, acc[i]);
      acc[i] = fmaf((float)v3[i], e3.y, acc[i]);
    }
  }
  for (; j < end; j += EPW) {
    const float2 e = ew[j];
    const half8v v = *(const half8v*)&hin[(size_t)__float_as_int(e.x) * F + c * 8];
#pragma unroll
    for (int i = 0; i < 8; ++i) acc[i] = fmaf((float)v[i], e.y, acc[i]);
  }

  // reduce across edge slots
#pragma unroll
  for (int d = LPE; d < 64; d <<= 1)
#pragma unroll
    for (int i = 0; i < 8; ++i) acc[i] += __shfl_xor(acc[i], d);

  if (lane < LPE) {
    const float4 b0 = *(const float4*)&bias[c * 8];
    const float4 b1 = *(const float4*)&bias[c * 8 + 4];
    float r[8];
    r[0] = fmaxf(acc[0] + b0.x, 0.f);
    r[1] = fmaxf(acc[1] + b0.y, 0.f);
    r[2] = fmaxf(acc[2] + b0.z, 0.f);
    r[3] = fmaxf(acc[3] + b0.w, 0.f);
    r[4] = fmaxf(acc[4] + b1.x, 0.f);
    r[5] = fmaxf(acc[5] + b1.y, 0.f);
    r[6] = fmaxf(acc[6] + b1.z, 0.f);
    r[7] = fmaxf(acc[7] + b1.w, 0.f);
    if constexpr (sizeof(OT) == 2) {
      half8v hv;
#pragma unroll
      for (int i = 0; i < 8; ++i) hv[i] = (_Float16)r[i];
      *(half8v*)&outp[(size_t)n * F + c * 8] = hv;
    } else {
      *(float4*)&outp[(size_t)n * F + c * 8]     = make_float4(r[0], r[1], r[2], r[3]);
      *(float4*)&outp[(size_t)n * F + c * 8 + 4] = make_float4(r[4], r[5], r[6], r[7]);
    }
  }
}

// ---------------- launch ----------------

extern "C" void kernel_launch(void* const* d_in, const int* in_sizes, int n_in,
                              void* d_out, int out_size, void* d_ws, size_t ws_size,
                              hipStream_t stream) {
  const float* x  = (const float*)d_in[0];
  const int*   ei = (const int*)d_in[1];
  const float* W1 = (const float*)d_in[2];
  const float* b1 = (const float*)d_in[3];
  const float* W2 = (const float*)d_in[4];
  const float* b2 = (const float*)d_in[5];
  float* out = (float*)d_out;

  const int F1 = in_sizes[3];           // 128
  const int F2 = in_sizes[5];           // 64
  const int F0 = in_sizes[2] / F1;      // 512
  const int N  = in_sizes[0] / F0;      // 100000
  const int E  = in_sizes[1] / 2;       // 1600000

  char* ws = (char*)d_ws;
  size_t off = 0;
  auto alloc = [&](size_t bytes) -> void* {
    void* p = ws + off;
    off = (off + bytes + 255) & ~(size_t)255;
    return p;
  };

  int*    cnt      = (int*)alloc((size_t)N * 4);
  int*    fillc    = (int*)alloc((size_t)N * 4);
  int*    rowstart = (int*)alloc((size_t)N * 4);
  float*  dinv     = (float*)alloc((size_t)N * 4);
  const int nb     = (N + SCAN_B - 1) / SCAN_B;
  int*    bsum     = (int*)alloc((size_t)nb * 4);
  float2* ew       = (float2*)alloc(((size_t)E + N) * 8);
  _Float16* h      = (_Float16*)alloc((size_t)N * F1 * 2);  // fp16 GEMM1 out
  _Float16* h1     = (_Float16*)alloc((size_t)N * F1 * 2);  // fp16 agg1 out (same RNE as r10's in-gemm cvt)
  _Float16* h2     = h;  // fp16 GEMM2 out, reuses h (dead after agg1)
  _Float16* W1t    = (_Float16*)alloc((size_t)F0 * F1 * 2);
  _Float16* W2t    = (_Float16*)alloc((size_t)F1 * F2 * 2);

  zero2_kernel<<<(N + 255) / 256, 256, 0, stream>>>(cnt, fillc, N);
  count_kernel<<<(E + 255) / 256, 256, 0, stream>>>(ei, cnt, E);
  scan1_kernel<<<nb, SCAN_B, 0, stream>>>(cnt, rowstart, bsum, dinv, N);
  scan2_kernel<<<1, SCAN_B, 0, stream>>>(bsum, nb);
  scan3_kernel<<<(N + 255) / 256, 256, 0, stream>>>(rowstart, bsum, N);
  fillself_kernel<<<(E + N + 255) / 256, 256, 0, stream>>>(ei, fillc, rowstart, cnt, dinv, ew, E, N);
  wconv2_kernel<<<(F0 * F1 + F1 * F2 + 255) / 256, 256, 0, stream>>>(
      W1, W1t, F0, F1, W2, W2t, F1, F2);

  // layer 1: h = fp16(x@W1) ; h1 = fp16(relu(agg(h) + b1))
  gemm_mfma_kernel<128, 128, float, _Float16><<<(N + 127) / 128, 512, 0, stream>>>(x, W1t, h, N, F0);
  {
    const long blocks = ((long)N * 64 + 255) / 256;
    agg_kernel<128, _Float16><<<(int)blocks, 256, 0, stream>>>(h, rowstart, cnt, ew, b1, h1, N);
  }

  // layer 2: h2 = fp16(h1@W2) ; out = relu(agg(h2) + b2)  (fp32)
  gemm_mfma_kernel<128, 64, _Float16, _Float16><<<(N + 127) / 128, 512, 0, stream>>>(h1, W2t, h2, N, F1);
  {
    const long blocks = ((long)N * 64 + 255) / 256;
    agg_kernel<64, float><<<(int)blocks, 256, 0, stream>>>(h2, rowstart, cnt, ew, b2, out, N);
  }
}